// Round 8
// baseline (688.571 us; speedup 1.0000x reference)
//
#include <hip/hip_runtime.h>

#define N_NODES 50000
#define N_EDGES 800000
#define D_IN    256
#define D_OUT   128
#define ELL_S   64                 // P(deg>=64)~1e-18 for Poisson(16)
#define GEMM_UNITS 391             // ceil(50000/128)
#define SCAT_UNITS 3125            // 800000/256
#define P2_UNITS (GEMM_UNITS + SCAT_UNITS)
#define NBLK    1024               // 4 blocks/CU x 256 CUs -> co-resident

typedef __attribute__((ext_vector_type(8))) short short8;
typedef __attribute__((ext_vector_type(4))) float floatx4;
typedef __attribute__((ext_vector_type(4))) unsigned int uintx4;

__device__ __forceinline__ unsigned short f2bf(float f) {
    unsigned int u = __float_as_uint(f);
    unsigned int r = (u + 0x7fffu + ((u >> 16) & 1u)) >> 16;   // RNE
    return (unsigned short)r;
}
__device__ __forceinline__ unsigned int pack2(float a, float b) {
    return (unsigned int)f2bf(a) | ((unsigned int)f2bf(b) << 16);
}
__device__ __forceinline__ float bfl(unsigned int u) { return __uint_as_float(u << 16); }
__device__ __forceinline__ float bfh(unsigned int u) { return __uint_as_float(u & 0xffff0000u); }

// Device-scope grid barrier. Safe because grid == NBLK is guaranteed
// co-resident by __launch_bounds__(256,4): 4 waves/EU cap -> <=128 VGPR,
// 10.25 KB LDS -> >=4 blocks/CU on 256 CUs. Producers use nontemporal stores
// (data at LLC/coherence point); fences cover the rest.
__device__ __forceinline__ void gbar(int* bar) {
    __syncthreads();
    if (threadIdx.x == 0) {
        __threadfence();
        atomicAdd(bar, 1);
        while (__hip_atomic_load(bar, __ATOMIC_ACQUIRE, __HIP_MEMORY_SCOPE_AGENT) < NBLK)
            __builtin_amdgcn_s_sleep(2);
        __threadfence();
    }
    __syncthreads();
}

// bf16 MFMA GEMM tile: 128 rows x 128 cols, 4 waves, A staged in LDS.
__device__ void gemm_tile(int tile, const float* __restrict__ x,
                          const unsigned short* __restrict__ bf,
                          unsigned short* __restrict__ h,
                          unsigned short (*As)[40]) {
    int tid  = threadIdx.x;
    int row0 = tile * 128;
    int wv   = tid >> 6;
    int lane = tid & 63;
    int quad = lane >> 4;
    int l15  = lane & 15;

    floatx4 acc[2][8];
#pragma unroll
    for (int i = 0; i < 2; i++)
#pragma unroll
        for (int j = 0; j < 8; j++) acc[i][j] = (floatx4){0.f, 0.f, 0.f, 0.f};

    int srow  = tid >> 1;
    int shalf = (tid & 1) * 16;
    const float* xrow = x + (size_t)(row0 + srow) * D_IN;
    bool svalid = (row0 + srow) < N_NODES;

    for (int k0 = 0; k0 < D_IN; k0 += 32) {
        uint4 p0 = make_uint4(0, 0, 0, 0), p1 = make_uint4(0, 0, 0, 0);
        if (svalid) {
            const float* src = xrow + k0 + shalf;
            float4 f0 = *(const float4*)(src + 0);
            float4 f1 = *(const float4*)(src + 4);
            float4 f2 = *(const float4*)(src + 8);
            float4 f3 = *(const float4*)(src + 12);
            p0 = make_uint4(pack2(f0.x, f0.y), pack2(f0.z, f0.w),
                            pack2(f1.x, f1.y), pack2(f1.z, f1.w));
            p1 = make_uint4(pack2(f2.x, f2.y), pack2(f2.z, f2.w),
                            pack2(f3.x, f3.y), pack2(f3.z, f3.w));
        }
        __syncthreads();
        *(uint4*)&As[srow][shalf + 0] = p0;
        *(uint4*)&As[srow][shalf + 8] = p1;
        __syncthreads();

        short8 a0 = *(const short8*)&As[wv * 32 + l15][quad * 8];
        short8 a1 = *(const short8*)&As[wv * 32 + 16 + l15][quad * 8];
        int kc = k0 >> 5;
#pragma unroll
        for (int ct = 0; ct < 8; ct++) {
            short8 b = *(const short8*)&bf[(size_t)(((ct * 8 + kc) * 64 + lane)) * 8];
            acc[0][ct] = __builtin_amdgcn_mfma_f32_16x16x32_bf16(a0, b, acc[0][ct], 0, 0, 0);
            acc[1][ct] = __builtin_amdgcn_mfma_f32_16x16x32_bf16(a1, b, acc[1][ct], 0, 0, 0);
        }
    }

#pragma unroll
    for (int rt = 0; rt < 2; rt++) {
        int grow0 = row0 + wv * 32 + rt * 16 + quad * 4;
#pragma unroll
        for (int r = 0; r < 4; r++) {
            int grow = grow0 + r;
            if (grow < N_NODES) {
#pragma unroll
                for (int ct = 0; ct < 8; ct++) {
                    __builtin_nontemporal_store(f2bf(acc[rt][ct][r]),
                                                &h[(size_t)grow * D_OUT + ct * 16 + l15]);
                }
            }
        }
    }
}

// Single-pass ELL scatter for one 256-edge chunk; per-chunk dtype detect
// (64-lane ballot on odd dwords of the src region — in-bounds either way).
__device__ void scatter_chunk(int chunk, const unsigned int* __restrict__ e32,
                              int* __restrict__ cnt, int* __restrict__ bucket) {
    int e0 = chunk * 256;
    int lane = threadIdx.x & 63;
    unsigned long long nz = __ballot(e32[2 * (e0 + lane) + 1] != 0u);
    int is64 = (nz == 0ULL);
    int e = e0 + threadIdx.x;
    int s, d;
    if (is64) {
        s = (int)((const long long*)e32)[e];
        d = (int)((const long long*)e32)[N_EDGES + e];
    } else {
        s = ((const int*)e32)[e];
        d = ((const int*)e32)[N_EDGES + e];
    }
    int pos = atomicAdd(&cnt[d], 1);
    if (pos < ELL_S) __builtin_nontemporal_store(s, &bucket[d * ELL_S + pos]);
}

__global__ __launch_bounds__(256, 4) void persistent_kernel(
    const float* __restrict__ x, const float* __restrict__ W,
    const void* __restrict__ ei, const float* __restrict__ bias,
    const float* __restrict__ pa, float* __restrict__ out,
    int* __restrict__ bars, int* __restrict__ cnt,
    unsigned short* __restrict__ bfrag, int* __restrict__ bucket,
    unsigned short* __restrict__ h, float* __restrict__ dinv) {
    __shared__ unsigned short As[128][40];
    __shared__ int wq;
    int tid = threadIdx.x;
    int bid = blockIdx.x;

    // ---- Phase 1: zero cnt (nt -> coherence point) + pack W fragments ----
    {
        int idx = bid * 256 + tid;
        if (idx < N_NODES) __builtin_nontemporal_store(0, &cnt[idx]);
        if (bid < 16) {
            int g = bid * 256 + tid;          // 0..4095
            int lane = g & 63;
            int kc   = (g >> 6) & 7;
            int ct   = g >> 9;
            int n  = ct * 16 + (lane & 15);
            int kb = kc * 32 + ((lane >> 4) & 3) * 8;
            unsigned int p[4];
#pragma unroll
            for (int jj = 0; jj < 4; jj++) {
                float a = W[(size_t)(kb + 2 * jj + 0) * D_OUT + n];
                float b = W[(size_t)(kb + 2 * jj + 1) * D_OUT + n];
                p[jj] = pack2(a, b);
            }
            uintx4 v = (uintx4){p[0], p[1], p[2], p[3]};
            __builtin_nontemporal_store(v, (uintx4*)&bfrag[(size_t)g * 8]);
        }
    }
    gbar(&bars[0]);

    // ---- Phase 2: dynamic queue over gemm tiles + scatter chunks ----
    for (;;) {
        if (tid == 0) wq = atomicAdd(&bars[3], 1);
        __syncthreads();
        int c = wq;
        __syncthreads();
        if (c >= P2_UNITS) break;
        if (c < GEMM_UNITS) gemm_tile(c, x, bfrag, h, As);
        else scatter_chunk(c - GEMM_UNITS, (const unsigned int*)ei, cnt, bucket);
    }
    gbar(&bars[1]);

    // ---- Phase 3: dinv table ----
    {
        int idx = bid * 256 + tid;
        if (idx < N_NODES) {
            float di = rsqrtf((float)(cnt[idx] + 1));   // +1 = self-loop
            __builtin_nontemporal_store(di, &dinv[idx]);
        }
    }
    gbar(&bars[2]);

    // ---- Phase 4: gather (1 wave per dst node, 2 bf16 ch/lane) ----
    {
        int lane = tid & 63;
        int gw = bid * 4 + (tid >> 6);
        int c2 = lane * 2;
        const unsigned int* hrow = (const unsigned int*)h + lane;  // row*64 + lane
        float2 bb = *(const float2*)&bias[c2];
        float2 aa = *(const float2*)&pa[c2];
        for (int d = gw; d < N_NODES; d += NBLK * 4) {
            int nraw = cnt[d];
            int n = nraw < ELL_S ? nraw : ELL_S;
            float di = dinv[d];
            unsigned int ud = hrow[(size_t)d * 64];
            float sl = di * di;
            float ax = bfl(ud) * sl, ay = bfh(ud) * sl;

            int   s_l = 0;
            float w_l = 0.f;
            if (lane < n) {
                s_l = bucket[d * ELL_S + lane];
                w_l = dinv[s_l] * di;
            }
            int k = 0;
            for (; k + 4 <= n; k += 4) {
                int s0 = __shfl(s_l, k + 0), s1 = __shfl(s_l, k + 1);
                int s2 = __shfl(s_l, k + 2), s3 = __shfl(s_l, k + 3);
                float w0 = __shfl(w_l, k + 0), w1 = __shfl(w_l, k + 1);
                float w2 = __shfl(w_l, k + 2), w3 = __shfl(w_l, k + 3);
                unsigned int u0 = hrow[(size_t)s0 * 64];
                unsigned int u1 = hrow[(size_t)s1 * 64];
                unsigned int u2 = hrow[(size_t)s2 * 64];
                unsigned int u3 = hrow[(size_t)s3 * 64];
                ax += bfl(u0) * w0; ay += bfh(u0) * w0;
                ax += bfl(u1) * w1; ay += bfh(u1) * w1;
                ax += bfl(u2) * w2; ay += bfh(u2) * w2;
                ax += bfl(u3) * w3; ay += bfh(u3) * w3;
            }
            for (; k < n; k++) {
                int s = __shfl(s_l, k);
                float wn = __shfl(w_l, k);
                unsigned int u = hrow[(size_t)s * 64];
                ax += bfl(u) * wn; ay += bfh(u) * wn;
            }
            float ox = ax + bb.x, oy = ay + bb.y;
            ox = ox > 0.f ? ox : aa.x * ox;
            oy = oy > 0.f ? oy : aa.y * oy;
            *(float2*)&out[(size_t)d * D_OUT + c2] = make_float2(ox, oy);
        }
    }
}

extern "C" void kernel_launch(void* const* d_in, const int* in_sizes, int n_in,
                              void* d_out, int out_size, void* d_ws, size_t ws_size,
                              hipStream_t stream) {
    const float* x  = (const float*)d_in[0];
    const void*  ei = d_in[1];
    const float* W  = (const float*)d_in[2];
    const float* b  = (const float*)d_in[3];
    const float* pa = (const float*)d_in[4];
    float* out = (float*)d_out;

    char* w = (char*)d_ws;
    int*   bars   = (int*)w;    w += 256;                 // bars[0..2] + queue ctr
    int*   cnt    = (int*)w;    w += N_NODES * 4;
    unsigned short* bfrag = (unsigned short*)w; w += 8 * 8 * 64 * 8 * 2;  // 64 KB
    int*   bucket = (int*)w;    w += (size_t)N_NODES * ELL_S * 4;         // 12.8 MB
    unsigned short* h = (unsigned short*)w; w += (size_t)N_NODES * D_OUT * 2;
    float* dinv   = (float*)w;  w += N_NODES * 4;

    (void)hipMemsetAsync(bars, 0, 256, stream);
    persistent_kernel<<<NBLK, 256, 0, stream>>>(x, W, ei, b, pa, out,
                                                bars, cnt, bfrag, bucket, h, dinv);
}

// Round 9
// 180.184 us; speedup vs baseline: 3.8215x; 3.8215x over previous
//
#include <hip/hip_runtime.h>

#define N_NODES 50000
#define N_EDGES 800000
#define D_IN    256
#define D_OUT   128
#define ELL_S   64                         // P(deg>=64)~1e-18 for Poisson(16)
#define GEMM_BLKS ((N_NODES + 127) / 128)  // 391
#define BKT_BLKS  ((N_EDGES + 255) / 256)  // 3125
#define CNT_PAD   50176                    // 98*512, for padded vector zeroing

typedef __attribute__((ext_vector_type(8))) short short8;
typedef __attribute__((ext_vector_type(4))) float floatx4;

__device__ __forceinline__ unsigned short f2bf(float f) {
    unsigned int u = __float_as_uint(f);
    unsigned int r = (u + 0x7fffu + ((u >> 16) & 1u)) >> 16;   // RNE
    return (unsigned short)r;
}
__device__ __forceinline__ unsigned int pack2(float a, float b) {
    return (unsigned int)f2bf(a) | ((unsigned int)f2bf(b) << 16);
}
__device__ __forceinline__ float bfl(unsigned int u) { return __uint_as_float(u << 16); }
__device__ __forceinline__ float bfh(unsigned int u) { return __uint_as_float(u & 0xffff0000u); }

__device__ __forceinline__ int load_idx(const void* ei, int i, int is64) {
    if (is64) return (int)((const long long*)ei)[i];
    return ((const int*)ei)[i];
}

// ---------------------------------------------------------------------------
// D1 prep (fat): block 0 = edge-dtype detect; blocks 1..16 = W fragment pack;
// blocks 17..114 = zero cnt.
// ---------------------------------------------------------------------------
__global__ __launch_bounds__(256) void prep_kernel(const unsigned int* __restrict__ e,
                                                   int* __restrict__ is64,
                                                   const float* __restrict__ W,
                                                   unsigned short* __restrict__ bf,
                                                   int* __restrict__ cnt) {
    int bid = blockIdx.x;
    int tid = threadIdx.x;
    if (bid == 0) {
        __shared__ int found32;
        if (tid == 0) found32 = 0;
        __syncthreads();
        for (int i = tid; i < 2048; i += 256)
            if (e[2 * i + 1] != 0u) found32 = 1;
        __syncthreads();
        if (tid == 0) *is64 = (found32 ? 0 : 1);
    } else if (bid <= 16) {
        int g = (bid - 1) * 256 + tid;     // 0..4095
        int lane = g & 63;
        int kc   = (g >> 6) & 7;
        int ct   = g >> 9;
        int n  = ct * 16 + (lane & 15);
        int kb = kc * 32 + ((lane >> 4) & 3) * 8;
        unsigned int p[4];
#pragma unroll
        for (int jj = 0; jj < 4; jj++) {
            float a = W[(size_t)(kb + 2 * jj + 0) * D_OUT + n];
            float b = W[(size_t)(kb + 2 * jj + 1) * D_OUT + n];
            p[jj] = pack2(a, b);
        }
        *(uint4*)&bf[(size_t)g * 8] = make_uint4(p[0], p[1], p[2], p[3]);
    } else {
        int i0 = ((bid - 17) * 256 + tid) * 2;   // < CNT_PAD
        *(int2*)&cnt[i0] = make_int2(0, 0);
    }
}

// ---------------------------------------------------------------------------
// D2 fat kernel: blocks [0, GEMM_BLKS) = bf16-MFMA GEMM (h = bf16(x@W));
// blocks [GEMM_BLKS, +BKT_BLKS) = single-pass ELL adjacency build.
// Disjoint bottlenecks (MFMA/LDS vs memory latency) -> co-scheduled overlap.
// ---------------------------------------------------------------------------
__global__ __launch_bounds__(256) void fused_kernel(const float* __restrict__ x,
                                                    const unsigned short* __restrict__ bf,
                                                    unsigned short* __restrict__ h,
                                                    const void* __restrict__ ei,
                                                    const int* __restrict__ is64p,
                                                    int* __restrict__ cnt,
                                                    int* __restrict__ bucket) {
    __shared__ unsigned short As[128][40];   // gemm A-tile (10 KB), +8 pad
    int tid = threadIdx.x;

    if (blockIdx.x >= GEMM_BLKS) {
        // ---- ELL bucket scatter ----
        int e = (blockIdx.x - GEMM_BLKS) * 256 + tid;
        if (e < N_EDGES) {
            int is64 = *is64p;
            int s = load_idx(ei, e, is64);
            int d = load_idx(ei, N_EDGES + e, is64);
            int pos = atomicAdd(&cnt[d], 1);
            if (pos < ELL_S) bucket[d * ELL_S + pos] = s;
        }
        return;
    }

    // ---- GEMM ----
    int row0 = blockIdx.x * 128;
    int w    = tid >> 6;
    int lane = tid & 63;
    int quad = lane >> 4;
    int l15  = lane & 15;

    floatx4 acc[2][8];
#pragma unroll
    for (int i = 0; i < 2; i++)
#pragma unroll
        for (int j = 0; j < 8; j++) acc[i][j] = (floatx4){0.f, 0.f, 0.f, 0.f};

    int srow  = tid >> 1;            // 0..127
    int shalf = (tid & 1) * 16;
    const float* xrow = x + (size_t)(row0 + srow) * D_IN;
    bool svalid = (row0 + srow) < N_NODES;

    for (int k0 = 0; k0 < D_IN; k0 += 32) {
        uint4 p0 = make_uint4(0, 0, 0, 0), p1 = make_uint4(0, 0, 0, 0);
        if (svalid) {
            const float* src = xrow + k0 + shalf;
            float4 f0 = *(const float4*)(src + 0);
            float4 f1 = *(const float4*)(src + 4);
            float4 f2 = *(const float4*)(src + 8);
            float4 f3 = *(const float4*)(src + 12);
            p0 = make_uint4(pack2(f0.x, f0.y), pack2(f0.z, f0.w),
                            pack2(f1.x, f1.y), pack2(f1.z, f1.w));
            p1 = make_uint4(pack2(f2.x, f2.y), pack2(f2.z, f2.w),
                            pack2(f3.x, f3.y), pack2(f3.z, f3.w));
        }
        __syncthreads();
        *(uint4*)&As[srow][shalf + 0] = p0;
        *(uint4*)&As[srow][shalf + 8] = p1;
        __syncthreads();

        short8 a0 = *(const short8*)&As[w * 32 + l15][quad * 8];
        short8 a1 = *(const short8*)&As[w * 32 + 16 + l15][quad * 8];
        int kc = k0 >> 5;
#pragma unroll
        for (int ct = 0; ct < 8; ct++) {
            short8 b = *(const short8*)&bf[(size_t)(((ct * 8 + kc) * 64 + lane)) * 8];
            acc[0][ct] = __builtin_amdgcn_mfma_f32_16x16x32_bf16(a0, b, acc[0][ct], 0, 0, 0);
            acc[1][ct] = __builtin_amdgcn_mfma_f32_16x16x32_bf16(a1, b, acc[1][ct], 0, 0, 0);
        }
    }

#pragma unroll
    for (int rt = 0; rt < 2; rt++) {
        int grow0 = row0 + w * 32 + rt * 16 + quad * 4;
#pragma unroll
        for (int r = 0; r < 4; r++) {
            int grow = grow0 + r;
            if (grow < N_NODES) {
#pragma unroll
                for (int ct = 0; ct < 8; ct++) {
                    h[(size_t)grow * D_OUT + ct * 16 + l15] = f2bf(acc[rt][ct][r]);
                }
            }
        }
    }
}

// D3: clean dinv table (one pass; avoids per-edge rsqrt on atomic-dirtied cnt).
__global__ __launch_bounds__(256) void dinv_kernel(const int* __restrict__ cnt,
                                                   float* __restrict__ dinv) {
    int i = blockIdx.x * 256 + threadIdx.x;
    if (i < N_NODES) dinv[i] = rsqrtf((float)(cnt[i] + 1));   // +1 = self-loop
}

// ---------------------------------------------------------------------------
// D4 gather: one wave64 per dst node; 2 bf16 channels/lane. ELL row read,
// clean dinv table, lane-parallel edge prefetch + shfl broadcast + 4x
// unrolled independent row loads. Self-loop + bias + PReLU.
// ---------------------------------------------------------------------------
__global__ __launch_bounds__(256) void gather_kernel(
    const unsigned short* __restrict__ h, const int* __restrict__ cnt,
    const float* __restrict__ dinv, const int* __restrict__ bucket,
    const float* __restrict__ bias, const float* __restrict__ pa,
    float* __restrict__ out) {
    int wave = (int)((blockIdx.x * blockDim.x + threadIdx.x) >> 6);
    int lane = threadIdx.x & 63;
    if (wave >= N_NODES) return;
    int d = wave;
    int nraw = cnt[d];
    int n = nraw < ELL_S ? nraw : ELL_S;
    float di = dinv[d];
    int c = lane * 2;
    const unsigned int* hrow = (const unsigned int*)h + lane;   // row*64 + lane
    unsigned int ud = hrow[(size_t)d * 64];
    float sl = di * di;
    float ax = bfl(ud) * sl, ay = bfh(ud) * sl;

    int   s_l = 0;
    float w_l = 0.f;
    if (lane < n) {
        s_l = bucket[d * ELL_S + lane];
        w_l = dinv[s_l] * di;
    }
    int k = 0;
    for (; k + 4 <= n; k += 4) {
        int s0 = __shfl(s_l, k + 0), s1 = __shfl(s_l, k + 1);
        int s2 = __shfl(s_l, k + 2), s3 = __shfl(s_l, k + 3);
        float w0 = __shfl(w_l, k + 0), w1 = __shfl(w_l, k + 1);
        float w2 = __shfl(w_l, k + 2), w3 = __shfl(w_l, k + 3);
        unsigned int u0 = hrow[(size_t)s0 * 64];
        unsigned int u1 = hrow[(size_t)s1 * 64];
        unsigned int u2 = hrow[(size_t)s2 * 64];
        unsigned int u3 = hrow[(size_t)s3 * 64];
        ax += bfl(u0) * w0; ay += bfh(u0) * w0;
        ax += bfl(u1) * w1; ay += bfh(u1) * w1;
        ax += bfl(u2) * w2; ay += bfh(u2) * w2;
        ax += bfl(u3) * w3; ay += bfh(u3) * w3;
    }
    for (; k < n; k++) {
        int s = __shfl(s_l, k);
        float wn = __shfl(w_l, k);
        unsigned int u = hrow[(size_t)s * 64];
        ax += bfl(u) * wn; ay += bfh(u) * wn;
    }
    float2 bb = *(const float2*)&bias[c];
    float2 aa = *(const float2*)&pa[c];
    float ox = ax + bb.x, oy = ay + bb.y;
    ox = ox > 0.f ? ox : aa.x * ox;
    oy = oy > 0.f ? oy : aa.y * oy;
    *(float2*)&out[(size_t)d * D_OUT + c] = make_float2(ox, oy);
}

extern "C" void kernel_launch(void* const* d_in, const int* in_sizes, int n_in,
                              void* d_out, int out_size, void* d_ws, size_t ws_size,
                              hipStream_t stream) {
    const float* x  = (const float*)d_in[0];
    const void*  ei = d_in[1];
    const float* W  = (const float*)d_in[2];
    const float* b  = (const float*)d_in[3];
    const float* pa = (const float*)d_in[4];
    float* out = (float*)d_out;

    char* w = (char*)d_ws;
    int*   is64   = (int*)w;    w += 256;
    int*   cnt    = (int*)w;    w += CNT_PAD * 4;
    float* dinv   = (float*)w;  w += N_NODES * 4;
    unsigned short* bfrag = (unsigned short*)w; w += 8 * 8 * 64 * 8 * 2;  // 64 KB
    int*   bucket = (int*)w;    w += (size_t)N_NODES * ELL_S * 4;         // 12.8 MB
    unsigned short* h = (unsigned short*)w; w += (size_t)N_NODES * D_OUT * 2;

    prep_kernel<<<1 + 16 + 98, 256, 0, stream>>>((const unsigned int*)ei, is64, W, bfrag, cnt);
    fused_kernel<<<GEMM_BLKS + BKT_BLKS, 256, 0, stream>>>(x, bfrag, h, ei, is64, cnt, bucket);
    dinv_kernel<<<(N_NODES + 255) / 256, 256, 0, stream>>>(cnt, dinv);
    gather_kernel<<<(N_NODES * 64 + 255) / 256, 256, 0, stream>>>(
        h, cnt, dinv, bucket, b, pa, out);
}